// Round 4
// baseline (399.146 us; speedup 1.0000x reference)
//
#include <hip/hip_runtime.h>
#include <cstdint>
#include <cmath>

#define HID 768
#define INNER 1536
#define NST 16
#define SEQ 2048
#define BATCH 2
#define MTOK 4096      // BATCH*SEQ
#define CHUNK 32
#define NCHUNK 64      // SEQ/CHUNK
#define LOG2E 1.44269504088896f

typedef unsigned short u16;
typedef __bf16 bf16x8 __attribute__((ext_vector_type(8)));
typedef float f32x4 __attribute__((ext_vector_type(4)));

__device__ __forceinline__ u16 f2b(float f) {
  union { float f; unsigned u; } a; a.f = f;
  unsigned r = a.u + 0x7FFFu + ((a.u >> 16) & 1u);
  return (u16)(r >> 16);
}
__device__ __forceinline__ float b2f(u16 h) {
  union { unsigned u; float f; } a; a.u = ((unsigned)h) << 16; return a.f;
}

__device__ __forceinline__ void gl2lds16(const u16* g, u16* l) {
  __builtin_amdgcn_global_load_lds(
      (const __attribute__((address_space(1))) void*)g,
      (__attribute__((address_space(3))) void*)l, 16, 0, 0);
}

// ---------------- LayerNorm + cast to bf16 ----------------
__global__ __launch_bounds__(256)
void ln_kernel(const float* __restrict__ x, const float* __restrict__ w,
               const float* __restrict__ b, u16* __restrict__ xn) {
  const long row = blockIdx.x;
  const float* xr = x + row * HID;
  const int t = threadIdx.x;
  float v0 = xr[t], v1 = xr[t + 256], v2 = xr[t + 512];
  float s1 = v0 + v1 + v2;
  float s2 = v0 * v0 + v1 * v1 + v2 * v2;
#pragma unroll
  for (int o = 32; o > 0; o >>= 1) { s1 += __shfl_down(s1, o); s2 += __shfl_down(s2, o); }
  __shared__ float r1[4], r2[4];
  if ((t & 63) == 0) { r1[t >> 6] = s1; r2[t >> 6] = s2; }
  __syncthreads();
  s1 = r1[0] + r1[1] + r1[2] + r1[3];
  s2 = r2[0] + r2[1] + r2[2] + r2[3];
  const float mu = s1 * (1.f / HID);
  float var = s2 * (1.f / HID) - mu * mu;
  const float rs = rsqrtf(var + 1e-5f);
  xn[row * HID + t]       = f2b((v0 - mu) * rs * w[t]       + b[t]);
  xn[row * HID + t + 256] = f2b((v1 - mu) * rs * w[t + 256] + b[t + 256]);
  xn[row * HID + t + 512] = f2b((v2 - mu) * rs * w[t + 512] + b[t + 512]);
}

// ---------------- fp32 W[K][N] -> bf16 Wt[Npad][K] (transpose+convert, zero pad) ----
__global__ __launch_bounds__(256)
void transpose_cvt(const float* __restrict__ W, u16* __restrict__ Wt,
                   int K, int N, int Npad) {
  __shared__ float tb[32][33];
  const int tx = threadIdx.x, ty = threadIdx.y;
  const int n0 = blockIdx.x * 32, k0 = blockIdx.y * 32;
#pragma unroll
  for (int r = 0; r < 4; ++r) {
    int kk = k0 + ty + r * 8;
    int nn = n0 + tx;
    tb[ty + r * 8][tx] = (nn < N) ? W[(long)kk * N + nn] : 0.f;
  }
  __syncthreads();
#pragma unroll
  for (int r = 0; r < 4; ++r) {
    int nn = n0 + ty + r * 8;
    int kk = k0 + tx;
    Wt[(long)nn * K + kk] = f2b(tb[tx][ty + r * 8]);
  }
}

// ---------------- GEMM: A[M][K] bf16 row-major, Bt[N][K] bf16, BMxBN tile ------
// 1D grid with XCD-aware swizzle: xcd = u&7 gets a contiguous bm-stripe x all bn,
// so each XCD's co-resident blocks share an L2-sized working set.
// EPI 0: cc<1536 -> xpu fp32; else -> sg = bf16(silu(v))        (gemm0)
// EPI 1: cc<16 -> Bm f32, cc<32 -> Cm f32, cc<Nstore -> dlt = bf16(softplus)
// EPI 2: O2 = bf16(v * sg[row,cc])                              (gemm2)
// EPI 3: O0[row*768+cc] = v + Ef[row*768+cc]                    (gemm3)
template <int BM, int BN, int NBX, int EPI>
__global__ __launch_bounds__(256)
void gemm_bt(const u16* __restrict__ A, const u16* __restrict__ Bt,
             float* __restrict__ O0, float* __restrict__ O1, u16* __restrict__ O2,
             const float* __restrict__ Ef, const u16* __restrict__ Eb,
             int K, int Nstore) {
  constexpr int NBY = 4096 / BM;    // M-tiles
  constexpr int PER = NBY / 8;      // bm-stripe per XCD
  constexpr int WTM = BM / 2;
  constexpr int WTN = BN / 2;
  constexpr int FI = WTM / 16;
  constexpr int FJ = WTN / 16;
  __shared__ u16 As[BM * 32];
  __shared__ u16 Bs[BN * 32];
  const int u = blockIdx.x;
  const int xcd = u & 7;
  const int s = u >> 3;
  const int bmt = xcd * PER + s / NBX;
  const int bnt = s % NBX;
  const long bm = (long)bmt * BM;
  const long bn = (long)bnt * BN;

  const int tid = threadIdx.x;
  const int lane = tid & 63;
  const int wave = tid >> 6;
  const int wm = wave >> 1, wn = wave & 1;
  const int l16 = lane & 15, l4 = lane >> 4;

  f32x4 acc[FI][FJ] = {};

  const int r0 = tid >> 2;          // 0..63
  const int kg = (tid & 3) * 8;     // 0,8,16,24

  for (int k0 = 0; k0 < K; k0 += 32) {
#pragma unroll
    for (int q = 0; q < BM / 64; ++q)
      gl2lds16(A + (bm + r0 + q * 64) * K + kg + k0, As + ((q * 256 + tid) * 8));
#pragma unroll
    for (int q = 0; q < BN / 64; ++q)
      gl2lds16(Bt + (bn + r0 + q * 64) * K + kg + k0, Bs + ((q * 256 + tid) * 8));
    __syncthreads();
    bf16x8 af[FI], bfr[FJ];
#pragma unroll
    for (int i = 0; i < FI; ++i)
      af[i] = *(const bf16x8*)&As[(wm * WTM + i * 16 + l16) * 32 + l4 * 8];
#pragma unroll
    for (int j = 0; j < FJ; ++j)
      bfr[j] = *(const bf16x8*)&Bs[(wn * WTN + j * 16 + l16) * 32 + l4 * 8];
#pragma unroll
    for (int i = 0; i < FI; ++i)
#pragma unroll
      for (int j = 0; j < FJ; ++j)
        acc[i][j] = __builtin_amdgcn_mfma_f32_16x16x32_bf16(af[i], bfr[j], acc[i][j], 0, 0, 0);
    __syncthreads();
  }

#pragma unroll
  for (int i = 0; i < FI; ++i) {
    const long rr = bm + wm * WTM + i * 16 + l4 * 4;
#pragma unroll
    for (int j = 0; j < FJ; ++j) {
      const int cc = (int)bn + wn * WTN + j * 16 + l16;
#pragma unroll
      for (int r = 0; r < 4; ++r) {
        const long row = rr + r;
        const float v = acc[i][j][r];
        if (EPI == 0) {
          if (cc < 1536) O0[row * 1536 + cc] = v;
          else {
            float sv = v / (1.f + __expf(-v));
            O2[row * 1536 + (cc - 1536)] = f2b(sv);
          }
        } else if (EPI == 1) {
          if (cc < 16) O0[row * 16 + cc] = v;
          else if (cc < 32) O1[row * 16 + (cc - 16)] = v;
          else if (cc < Nstore) {
            float sp = (v > 20.f) ? v : log1pf(__expf(v));
            O2[row * 1536 + (cc - 32)] = f2b(sp);
          }
        } else if (EPI == 2) {
          float g = b2f(Eb[row * 1536 + cc]);
          O2[row * 1536 + cc] = f2b(v * g);
        } else {
          O0[row * 768 + cc] = v + Ef[row * 768 + cc];
        }
      }
    }
  }
}

// ---------------- depthwise causal conv(K=4) + SiLU -> bf16 ----------------
__global__ __launch_bounds__(256)
void conv_silu(const float* __restrict__ xpu, const float* __restrict__ cw,
               u16* __restrict__ ub) {
  const int c = blockIdx.x * 256 + threadIdx.x;
  const long m = blockIdx.y;
  const int t = (int)(m & (SEQ - 1));
  const float w0 = cw[c * 4 + 0], w1 = cw[c * 4 + 1], w2 = cw[c * 4 + 2], w3 = cw[c * 4 + 3];
  float acc = w3 * xpu[m * 1536 + c];
  if (t >= 1) acc += w2 * xpu[(m - 1) * 1536 + c];
  if (t >= 2) acc += w1 * xpu[(m - 2) * 1536 + c];
  if (t >= 3) acc += w0 * xpu[(m - 3) * 1536 + c];
  const float s = acc / (1.f + __expf(-acc));
  ub[m * 1536 + c] = f2b(s);
}

// ---------------- scan phase A: per-chunk (P, Q) from h=0, 4 states/thread ------
__global__ __launch_bounds__(256)
void scan_phaseA(const u16* __restrict__ dlt, const u16* __restrict__ ub,
                 const float* __restrict__ Bm, const float* __restrict__ A_log,
                 float* __restrict__ P, float* __restrict__ Q) {
  const int tid = threadIdx.x;
  const int cl = tid >> 2;
  const int sg = tid & 3;
  const int c = blockIdx.x * 64 + cl;
  const int b = blockIdx.y;
  const int ch = blockIdx.z;
  float a2[4];
#pragma unroll
  for (int j = 0; j < 4; ++j) a2[j] = -__expf(A_log[sg * 4 + j]) * LOG2E;
  float h[4] = {0.f, 0.f, 0.f, 0.f};
  float sumd = 0.f;
  const long base = (long)b * SEQ + (long)ch * CHUNK;
  for (int t = 0; t < CHUNK; ++t) {
    const long m = base + t;
    const float d = b2f(dlt[m * 1536 + c]);
    const float du = d * b2f(ub[m * 1536 + c]);
    sumd += d;
    const f32x4 Bv = *(const f32x4*)&Bm[m * 16 + sg * 4];
#pragma unroll
    for (int j = 0; j < 4; ++j) {
      const float e = exp2f(a2[j] * d);
      h[j] = e * h[j] + du * Bv[j];
    }
  }
  const long sb = (((long)b * NCHUNK + ch) * NST + sg * 4) * 1536 + c;
#pragma unroll
  for (int j = 0; j < 4; ++j) {
    Q[sb + (long)j * 1536] = h[j];
    P[sb + (long)j * 1536] = exp2f(a2[j] * sumd);
  }
}

// ---------------- scan phase B: serial combine over chunks (hs aliases P) -------
__global__ __launch_bounds__(256)
void scan_phaseB(float* __restrict__ P, const float* __restrict__ Q) {
  const long g = (long)blockIdx.x * 256 + threadIdx.x;   // BATCH*NST*INNER
  const int c = (int)(g % 1536);
  const int n = (int)((g / 1536) % NST);
  const int b = (int)(g / (1536 * NST));
  float h = 0.f;
  for (int ch = 0; ch < NCHUNK; ++ch) {
    const long idx = (((long)b * NCHUNK + ch) * NST + n) * 1536 + c;
    const float p = P[idx];
    const float q = Q[idx];
    P[idx] = h;              // hs written in place of P (read-before-write)
    h = p * h + q;
  }
}

// ---------------- scan phase C: replay with true h_start, emit ys bf16 ----------
__global__ __launch_bounds__(256)
void scan_phaseC(const u16* __restrict__ dlt, const u16* __restrict__ ub,
                 const float* __restrict__ Bm, const float* __restrict__ Cm,
                 const float* __restrict__ A_log, const float* __restrict__ Dv,
                 const float* __restrict__ hs, u16* __restrict__ ys) {
  const int tid = threadIdx.x;
  const int cl = tid >> 2;
  const int sg = tid & 3;
  const int c = blockIdx.x * 64 + cl;
  const int b = blockIdx.y;
  const int ch = blockIdx.z;
  float a2[4];
#pragma unroll
  for (int j = 0; j < 4; ++j) a2[j] = -__expf(A_log[sg * 4 + j]) * LOG2E;
  float h[4];
  const long sb = (((long)b * NCHUNK + ch) * NST + sg * 4) * 1536 + c;
#pragma unroll
  for (int j = 0; j < 4; ++j) h[j] = hs[sb + (long)j * 1536];
  const float Dc = Dv[c];
  const long base = (long)b * SEQ + (long)ch * CHUNK;
  for (int t = 0; t < CHUNK; ++t) {
    const long m = base + t;
    const float d = b2f(dlt[m * 1536 + c]);
    const float uu = b2f(ub[m * 1536 + c]);
    const float du = d * uu;
    const f32x4 Bv = *(const f32x4*)&Bm[m * 16 + sg * 4];
    const f32x4 Cv = *(const f32x4*)&Cm[m * 16 + sg * 4];
    float y = (sg == 0) ? Dc * uu : 0.f;
#pragma unroll
    for (int j = 0; j < 4; ++j) {
      const float e = exp2f(a2[j] * d);
      h[j] = e * h[j] + du * Bv[j];
      y += h[j] * Cv[j];
    }
    y += __shfl_xor(y, 1);
    y += __shfl_xor(y, 2);
    if (sg == 0) ys[m * 1536 + c] = f2b(y);
  }
}

extern "C" void kernel_launch(void* const* d_in, const int* in_sizes, int n_in,
                              void* d_out, int out_size, void* d_ws, size_t ws_size,
                              hipStream_t stream) {
  const float* x     = (const float*)d_in[0];
  const float* nw    = (const float*)d_in[1];
  const float* nb    = (const float*)d_in[2];
  const float* W_in  = (const float*)d_in[3];
  const float* cw    = (const float*)d_in[4];
  const float* W_xp  = (const float*)d_in[5];
  const float* A_log = (const float*)d_in[6];
  const float* Dv    = (const float*)d_in[7];
  const float* W_so  = (const float*)d_in[8];
  const float* W_out = (const float*)d_in[9];
  float* out = (float*)d_out;

  char* w = (char*)d_ws;
  auto alloc = [&](size_t bytes) {
    char* p = w;
    w += (bytes + 255) & ~(size_t)255;
    return p;
  };
  u16*   xn    = (u16*)  alloc((size_t)MTOK * HID * 2);
  u16*   WtIn  = (u16*)  alloc((size_t)3072 * 768 * 2);
  float* xpu   = (float*)alloc((size_t)MTOK * 1536 * 4);   // u half, fp32 (conv input)
  u16*   sg    = (u16*)  alloc((size_t)MTOK * 1536 * 2);   // silu(gate), bf16
  u16*   ub    = (u16*)  alloc((size_t)MTOK * 1536 * 2);   // silu(conv(u)), bf16
  u16*   WtXp  = (u16*)  alloc((size_t)1664 * 1536 * 2);
  float* Bmv   = (float*)alloc((size_t)MTOK * 16 * 4);
  float* Cmv   = (float*)alloc((size_t)MTOK * 16 * 4);
  u16*   dlt   = (u16*)  alloc((size_t)MTOK * 1536 * 2);   // softplus(delta), bf16
  float* P     = (float*)alloc((size_t)BATCH * NCHUNK * NST * 1536 * 4);  // becomes hs
  float* Q     = (float*)alloc((size_t)BATCH * NCHUNK * NST * 1536 * 4);
  u16*   ys    = (u16*)  alloc((size_t)MTOK * 1536 * 2);
  u16*   WtSo  = (u16*)  alloc((size_t)1536 * 1536 * 2);
  u16*   zb    = (u16*)  alloc((size_t)MTOK * 1536 * 2);
  u16*   WtOut = (u16*)  alloc((size_t)768 * 1536 * 2);

  ln_kernel<<<MTOK, 256, 0, stream>>>(x, nw, nb, xn);
  transpose_cvt<<<dim3(3072 / 32, 768 / 32), dim3(32, 8), 0, stream>>>(W_in, WtIn, 768, 3072, 3072);
  transpose_cvt<<<dim3(1664 / 32, 1536 / 32), dim3(32, 8), 0, stream>>>(W_xp, WtXp, 1536, 1568, 1664);
  transpose_cvt<<<dim3(1536 / 32, 1536 / 32), dim3(32, 8), 0, stream>>>(W_so, WtSo, 1536, 1536, 1536);
  transpose_cvt<<<dim3(768 / 32, 1536 / 32), dim3(32, 8), 0, stream>>>(W_out, WtOut, 1536, 768, 768);

  // gemm0: 4096x3072, K=768, 128x128, 24*32 = 768 blocks
  gemm_bt<128, 128, 24, 0><<<768, 256, 0, stream>>>(xn, WtIn, xpu, nullptr, sg, nullptr, nullptr, 768, 3072);
  conv_silu<<<dim3(6, MTOK), 256, 0, stream>>>(xpu, cw, ub);
  // gemm1: 4096x1664, K=1536, 128x64, 26*32 = 832 blocks
  gemm_bt<128, 64, 26, 1><<<832, 256, 0, stream>>>(ub, WtXp, Bmv, Cmv, dlt, nullptr, nullptr, 1536, 1568);
  scan_phaseA<<<dim3(24, 2, NCHUNK), 256, 0, stream>>>(dlt, ub, Bmv, A_log, P, Q);
  scan_phaseB<<<192, 256, 0, stream>>>(P, Q);
  scan_phaseC<<<dim3(24, 2, NCHUNK), 256, 0, stream>>>(dlt, ub, Bmv, Cmv, A_log, Dv, P, ys);
  // gemm2: 4096x1536, K=1536, 128x64, 24*32 = 768 blocks
  gemm_bt<128, 64, 24, 2><<<768, 256, 0, stream>>>(ys, WtSo, nullptr, nullptr, zb, nullptr, sg, 1536, 1536);
  // gemm3: 4096x768, K=1536, 64x64, 12*64 = 768 blocks
  gemm_bt<64, 64, 12, 3><<<768, 256, 0, stream>>>(zb, WtOut, out, nullptr, nullptr, x, nullptr, 1536, 768);
}